// Round 4
// baseline (962.065 us; speedup 1.0000x reference)
//
#include <hip/hip_runtime.h>
#include <hip/hip_bf16.h>

// TrittentionCube on MI355X. B=1, P=256, D=512, N=8, H=64.
// Input dtype (bf16 vs fp32) resolved at RUNTIME via a probe kernel; both
// pipeline variants are launched, gated on the probe flag (graph-safe:
// deterministic for fixed inputs). Workspace use: 3.57 MB total.
//
// Factorization:
//   ta..te[p,n,h] = x @ W_* + b_*                  (batched GEMMs, bf16 out)
//   tbs[q,j]      = (1/64) sum_n tb[q,n,j]         (fp32)
//   s1t[r][(i,j)] = sum_{n,k} tc[r,(n,k)] W_K[n,i,j,k]  (GEMM w/ strided B, bf16)
//   per (n,r) block:  c[q,i] = sum_j tbs[q,j] s1t[r][(i,j)]      (fused, LDS fp32)
//     logits s(p,q) = ta[p,n,:].c[q,:]  (tbs pre-scaled by 1/H); e=exp(s) for p<q<r
//     (O(1) logits -> no max subtraction; clamp +-60 defensively)
//     T[p,g] = sum_q e*te[q,n,g]; Z = sum e
//     S[g,h] = sum_p T[p,g]*td[p,n,h];  z[r,n,f] = (1/Z) sum_{g,h} S[g,h]*W_V[n,h,g,f]
//   out[r,d] = zb(256x512) @ W_O(512x512) + b_O

typedef __hip_bfloat16 bf16;

__device__ __forceinline__ float ldf(const float* p){ return *p; }
__device__ __forceinline__ float ldf(const bf16* p){ return __bfloat162float(*p); }
__device__ __forceinline__ void  stf(float* p, float v){ *p = v; }
__device__ __forceinline__ void  stf(bf16*  p, float v){ *p = __float2bfloat16(v); }

__device__ __forceinline__ unsigned bfbits(float x){
  bf16 b = __float2bfloat16(x);
  return (unsigned)*reinterpret_cast<unsigned short*>(&b);
}

// Decide input dtype: flag=1 if bf16, 0 if fp32. Looks at low 16 bits of the
// first 256 32-bit words of x: for a bf16 array these are sane bf16 values
// (exponent near 127); for an fp32 array they are uniform mantissa bits.
__global__ void dtype_probe(const unsigned* __restrict__ x, int* __restrict__ flag)
{
  int t = threadIdx.x;              // 64 threads
  int cnt = 0;
  #pragma unroll
  for (int k = 0; k < 4; k++) {
    unsigned w = x[t*4 + k];
    unsigned lo = w & 0xFFFFu;
    unsigned e  = (lo >> 7) & 0xFFu;
    if (lo == 0u || (e >= 90u && e <= 145u)) cnt++;
  }
  #pragma unroll
  for (int off = 32; off; off >>= 1) cnt += __shfl_down(cnt, off);
  if (t == 0) *flag = (cnt >= 160) ? 1 : 0;
}

// Generic 64x64-tile GEMM: C = A(M x K) @ B(K x Ncols) (+ bias[col]).
// BTRANS (step-4 only): B element(kr,col) = B[(kr>>6)*262144 + col*64 + (kr&63)]
// i.e. the (n,k)-contracted read of W_K[n][i][j][k] with col=(i,j).
template<typename TA, typename TB, typename TC, bool BIAS, bool BTRANS>
__global__ __launch_bounds__(256) void gemm_tile(
    const int* __restrict__ gate, int want,
    const TA* __restrict__ A, const TB* __restrict__ B, TC* __restrict__ C,
    const TB* __restrict__ bias,
    int Ncols, int K, int lda, int ldc,
    long sA, long sB, long sC, long sBias)
{
  if (*gate != want) return;
  const int bz = blockIdx.z;
  A += bz * sA; B += bz * sB; C += bz * sC;
  const int m0 = blockIdx.y * 64, n0 = blockIdx.x * 64;
  __shared__ float As[16][64];   // [k][m]
  __shared__ float Bs[16][64];   // [k][n]
  const int t = threadIdx.x;
  const int tx = t & 15, ty = t >> 4;
  float acc[4][4] = {};
  for (int k0 = 0; k0 < K; k0 += 16) {
    { // stage A tile (transposed to [k][m])
      int m = t >> 2, kk = (t & 3) * 4;
      const TA* ap = A + (size_t)(m0 + m) * lda + (k0 + kk);
      float a0 = ldf(ap+0), a1 = ldf(ap+1), a2 = ldf(ap+2), a3 = ldf(ap+3);
      As[kk+0][m] = a0; As[kk+1][m] = a1; As[kk+2][m] = a2; As[kk+3][m] = a3;
    }
    { // stage B tile
      int kk = t >> 4, nn = (t & 15) * 4;
      if constexpr (BTRANS) {
        int kr = k0 + kk;
        const TB* bp = B + (size_t)(kr >> 6) * 262144 + (size_t)(kr & 63);
        Bs[kk][nn+0] = ldf(bp + (size_t)(n0+nn+0) * 64);
        Bs[kk][nn+1] = ldf(bp + (size_t)(n0+nn+1) * 64);
        Bs[kk][nn+2] = ldf(bp + (size_t)(n0+nn+2) * 64);
        Bs[kk][nn+3] = ldf(bp + (size_t)(n0+nn+3) * 64);
      } else {
        const TB* bp = B + (size_t)(k0 + kk) * Ncols + (n0 + nn);
        Bs[kk][nn+0] = ldf(bp+0); Bs[kk][nn+1] = ldf(bp+1);
        Bs[kk][nn+2] = ldf(bp+2); Bs[kk][nn+3] = ldf(bp+3);
      }
    }
    __syncthreads();
    #pragma unroll
    for (int kk = 0; kk < 16; kk++) {
      float4 a4 = *reinterpret_cast<const float4*>(&As[kk][ty*4]);
      float4 b4 = *reinterpret_cast<const float4*>(&Bs[kk][tx*4]);
      float av[4] = {a4.x, a4.y, a4.z, a4.w};
      float bv[4] = {b4.x, b4.y, b4.z, b4.w};
      #pragma unroll
      for (int im = 0; im < 4; im++)
        #pragma unroll
        for (int in = 0; in < 4; in++) acc[im][in] += av[im] * bv[in];
    }
    __syncthreads();
  }
  #pragma unroll
  for (int im = 0; im < 4; im++) {
    TC* cp = C + (size_t)(m0 + ty*4 + im) * ldc + n0 + tx*4;
    #pragma unroll
    for (int in = 0; in < 4; in++) {
      float v = acc[im][in];
      if constexpr (BIAS) v += ldf(bias + bz * sBias + n0 + tx*4 + in);
      stf(cp + in, v);
    }
  }
}

// tbs[q][j] = (1/64) * sum_n tb[q][n][j]   (tb bf16 -> fp32, logit scale folded in)
__global__ __launch_bounds__(256) void tbs_kern(const bf16* __restrict__ tb,
                                                float* __restrict__ tbs)
{
  int t = blockIdx.x * 256 + threadIdx.x;   // 0..16383
  int q = t >> 6, j = t & 63;
  const bf16* src = tb + q * 512 + j;
  float s = 0.f;
  #pragma unroll
  for (int n = 0; n < 8; n++) s += __bfloat162float(src[n * 64]);
  tbs[t] = s * 0.015625f;
}

// Per-(n,r): fused c-compute + streaming softmax + T + S-reorder + W_V contraction.
// LDS 64 KB: phase A/loop: c rows (slot q-1) sm[0..16255], scr sm[16256..16383];
//            phase B: T rows bf16 bytes [0,32512); phase C: S fp32 sm[10240..14335].
template<typename TW>
__global__ __launch_bounds__(256) void tri_attn(
    const int* __restrict__ gate, int want,
    const bf16* __restrict__ ta,   // [p][n][64] bf16
    const bf16* __restrict__ td,   // [p][n][64] bf16
    const bf16* __restrict__ te,   // [q][n][64] bf16
    const float* __restrict__ tbs, // [q][64] fp32, pre-scaled 1/64
    const bf16* __restrict__ s1t,  // [r][(i,j)] bf16, j fastest
    const TW*   __restrict__ WV,   // [n][h][g][f] input dtype
    bf16* __restrict__ zb)         // [r][n*64+f] bf16
{
  if (*gate != want) return;
  __shared__ float sm[16384];
  const int bx = blockIdx.x;
  const int n = bx & 7;               // n -> XCD affinity (W_V[n] L2 residency)
  const int r = 255 - (bx >> 3);      // big-r first
  const int t = threadIdx.x;
  bf16* zrow = zb + r * 512 + n * 64;
  if (r < 2) {                        // no valid (p<q<r): z = 0
    if (t < 64) stf(zrow + t, 0.f);
    return;
  }

  // Phase A1: c[q][i] = sum_j tbs[q,j]*s1t[r][(i,j)] -> sm[(q-1)*64+i], q in [1,r-1]
  {
    const int q = t;
    if (q >= 1 && q < r) {
      float tbr[64];
      const float4* tp = reinterpret_cast<const float4*>(tbs + q * 64);
      #pragma unroll
      for (int j4 = 0; j4 < 16; j4++) {
        float4 v = tp[j4];
        tbr[4*j4]=v.x; tbr[4*j4+1]=v.y; tbr[4*j4+2]=v.z; tbr[4*j4+3]=v.w;
      }
      const uint4* s1r = reinterpret_cast<const uint4*>(s1t + (size_t)r * 4096);
      float* crow = sm + (q - 1) * 64;
      for (int i = 0; i < 64; i++) {
        float acc = 0.f;
        #pragma unroll
        for (int j8 = 0; j8 < 8; j8++) {
          uint4 u = s1r[i*8 + j8];     // wave-uniform address -> broadcast
          unsigned w4[4] = {u.x, u.y, u.z, u.w};
          #pragma unroll
          for (int k2 = 0; k2 < 4; k2++) {
            acc += tbr[8*j8 + 2*k2    ] * __uint_as_float(w4[k2] << 16);
            acc += tbr[8*j8 + 2*k2 + 1] * __uint_as_float(w4[k2] & 0xFFFF0000u);
          }
        }
        crow[i] = acc;
      }
    }
  }
  // Phase A2: ta[p,n,:] into registers
  const int p = t;
  float tap[64];
  {
    const uint4* ap = reinterpret_cast<const uint4*>(ta + (size_t)p * 512 + n * 64);
    #pragma unroll
    for (int j8 = 0; j8 < 8; j8++) {
      uint4 u = ap[j8];
      unsigned w4[4] = {u.x, u.y, u.z, u.w};
      #pragma unroll
      for (int k2 = 0; k2 < 4; k2++) {
        tap[8*j8 + 2*k2]     = __uint_as_float(w4[k2] << 16);
        tap[8*j8 + 2*k2 + 1] = __uint_as_float(w4[k2] & 0xFFFF0000u);
      }
    }
  }
  __syncthreads();                    // c visible

  float T[64];
  #pragma unroll
  for (int g = 0; g < 64; g++) T[g] = 0.f;
  float Zp = 0.f;
  const int wbase = p & ~63;          // wave-uniform triangular skip
  for (int qq = wbase + 1; qq < r; qq++) {
    const float4* cq = reinterpret_cast<const float4*>(sm + (qq - 1) * 64);
    float s0=0.f, s1=0.f, s2=0.f, s3=0.f;
    #pragma unroll
    for (int i4 = 0; i4 < 16; i4++) {
      float4 c4 = cq[i4];
      s0 += tap[4*i4+0]*c4.x; s1 += tap[4*i4+1]*c4.y;
      s2 += tap[4*i4+2]*c4.z; s3 += tap[4*i4+3]*c4.w;
    }
    float sv = (s0 + s1) + (s2 + s3);            // already /64 via tbs
    sv = fminf(fmaxf(sv, -60.f), 60.f);          // defensive: fmaxf eats NaN
    float e = (p < qq) ? __expf(sv) : 0.f;
    Zp += e;
    const uint4* tq = reinterpret_cast<const uint4*>(te + (size_t)qq * 512 + n * 64);
    #pragma unroll
    for (int j8 = 0; j8 < 8; j8++) {
      uint4 u = tq[j8];                // wave-uniform -> broadcast
      unsigned w4[4] = {u.x, u.y, u.z, u.w};
      #pragma unroll
      for (int k2 = 0; k2 < 4; k2++) {
        T[8*j8 + 2*k2]     += e * __uint_as_float(w4[k2] << 16);
        T[8*j8 + 2*k2 + 1] += e * __uint_as_float(w4[k2] & 0xFFFF0000u);
      }
    }
  }
  #pragma unroll
  for (int off = 32; off; off >>= 1) Zp += __shfl_down(Zp, off);
  __syncthreads();                    // all c reads done

  // Phase B: T row p -> bf16 at bytes [p*128, p*128+128); rows >= r-1 are zeros.
  unsigned* Tb = reinterpret_cast<unsigned*>(sm);
  if (p <= 253) {                     // rows 254/255 never read in phase C
    #pragma unroll
    for (int w2 = 0; w2 < 32; w2++)
      Tb[p*32 + w2] = (bfbits(T[2*w2+1]) << 16) | bfbits(T[2*w2]);
  }
  float* scr = sm + 16256;            // disjoint from T bytes [0,32512) and S
  const int lane = t & 63, wid = t >> 6;
  if (lane == 0) scr[wid] = Zp;
  __syncthreads();
  const float rinv = 1.f / (scr[0] + scr[1] + scr[2] + scr[3]);

  // Phase C: S[g][h] = sum_{p<=r-2} T[p,g]*td[p,n,h]; thread: h=lane, g in [wid*16,+16)
  const int h = lane, g0 = wid * 16;
  float sacc[16];
  #pragma unroll
  for (int k = 0; k < 16; k++) sacc[k] = 0.f;
  const bf16* tdn = td + n * 64 + h;
  const char* smc = reinterpret_cast<const char*>(sm);
  for (int pp = 0; pp <= r - 2; pp++) {
    float tdv = __bfloat162float(tdn[(size_t)pp * 512]);   // coalesced over lanes
    const uint4* tp = reinterpret_cast<const uint4*>(smc + pp*128 + wid*32);
    uint4 u0 = tp[0], u1 = tp[1];
    unsigned w8[8] = {u0.x, u0.y, u0.z, u0.w, u1.x, u1.y, u1.z, u1.w};
    #pragma unroll
    for (int k2 = 0; k2 < 8; k2++) {
      sacc[2*k2]   += __uint_as_float(w8[k2] << 16)         * tdv;
      sacc[2*k2+1] += __uint_as_float(w8[k2] & 0xFFFF0000u) * tdv;
    }
  }
  float* Sb = sm + 10240;             // bytes [40960,57344) — disjoint from T, scr
  #pragma unroll
  for (int k = 0; k < 16; k++) Sb[(g0 + k) * 64 + h] = sacc[k];
  __syncthreads();

  // Phase D: z[f] partial over g in [g0,g0+16): sum_{g,h} S[g,h]*WV[n,h,g,f]
  const int f = lane;
  const TW* wvn = WV + (size_t)n * 262144 + f;
  float zacc = 0.f;
  for (int k = 0; k < 16; k++) {
    const float* Srow = Sb + (g0 + k) * 64;
    const TW* wvg = wvn + (size_t)(g0 + k) * 64;
    #pragma unroll
    for (int h4 = 0; h4 < 16; h4++) {
      float4 s4 = *reinterpret_cast<const float4*>(Srow + h4 * 4);
      zacc += s4.x * ldf(wvg + (size_t)(4*h4+0) * 4096);
      zacc += s4.y * ldf(wvg + (size_t)(4*h4+1) * 4096);
      zacc += s4.z * ldf(wvg + (size_t)(4*h4+2) * 4096);
      zacc += s4.w * ldf(wvg + (size_t)(4*h4+3) * 4096);
    }
  }
  if (wid >= 2) scr[(wid - 2) * 64 + f] = zacc;
  __syncthreads();
  if (wid < 2) zacc += scr[wid * 64 + f];
  __syncthreads();
  if (wid == 1) scr[f] = zacc;
  __syncthreads();
  if (wid == 0) stf(zrow + f, (zacc + scr[f]) * rinv);
}

extern "C" void kernel_launch(void* const* d_in, const int* in_sizes, int n_in,
                              void* d_out, int out_size, void* d_ws, size_t ws_size,
                              hipStream_t stream)
{
  (void)in_sizes; (void)n_in; (void)out_size; (void)ws_size;
  // Workspace layout (bytes), total 3,735,808 B (~3.57 MB):
  //   flag  int  [0, 4)
  //   tproj bf16 [256, 1310976)     5 x [256][8][64]  (ta,tb,tc,td,te)
  //   tbs   fp32 [1310976, 1376512)
  //   s1t   bf16 [1376512, 3473664) [256][4096]
  //   zbb   bf16 [3473664, 3735808) [256][512]
  char* wsb = (char*)d_ws;
  int*   flag = (int*)wsb;
  bf16*  tproj = (bf16*)(wsb + 256);
  float* tbsb  = (float*)(wsb + 1310976);
  bf16*  s1t   = (bf16*) (wsb + 1376512);
  bf16*  zbb   = (bf16*) (wsb + 3473664);
  const long TE = 131072;   // elements per projection tensor

  // 0) input-dtype probe (1 = bf16, 0 = fp32)
  dtype_probe<<<1, 64, 0, stream>>>((const unsigned*)d_in[0], flag);

  // 1) projections: t*[p,n,h] = x @ W[n] + b[n]  (both dtype variants, gated)
  for (int j = 0; j < 5; j++) {
    gemm_tile<bf16, bf16, bf16, true, false><<<dim3(1,4,8), 256, 0, stream>>>(
        flag, 1, (const bf16*)d_in[0], (const bf16*)d_in[1 + 2*j], tproj + j*TE,
        (const bf16*)d_in[2 + 2*j], 64, 512, 512, 512, 0, 32768, 64, 64);
    gemm_tile<float, float, bf16, true, false><<<dim3(1,4,8), 256, 0, stream>>>(
        flag, 0, (const float*)d_in[0], (const float*)d_in[1 + 2*j], tproj + j*TE,
        (const float*)d_in[2 + 2*j], 64, 512, 512, 512, 0, 32768, 64, 64);
  }
  // 2) tbs = (1/64) sum_n tb
  tbs_kern<<<64, 256, 0, stream>>>(tproj + 1*TE, tbsb);
  // 3) s1t[r][(i,j)] = sum_{(n,k)} tc[r,(n,k)] * W_K[n][i][j][k]  (strided-B GEMM)
  gemm_tile<bf16, bf16, bf16, false, true><<<dim3(64,4,1), 256, 0, stream>>>(
      flag, 1, tproj + 2*TE, (const bf16*)d_in[12], s1t, (const bf16*)nullptr,
      4096, 512, 512, 4096, 0, 0, 0, 0);
  gemm_tile<bf16, float, bf16, false, true><<<dim3(64,4,1), 256, 0, stream>>>(
      flag, 0, tproj + 2*TE, (const float*)d_in[12], s1t, (const float*)nullptr,
      4096, 512, 512, 4096, 0, 0, 0, 0);
  // 4) per-(n,r) fused c + softmax + S + W_V -> zbb
  tri_attn<bf16><<<2048, 256, 0, stream>>>(
      flag, 1, tproj, tproj + 3*TE, tproj + 4*TE, tbsb, s1t,
      (const bf16*)d_in[11], zbb);
  tri_attn<float><<<2048, 256, 0, stream>>>(
      flag, 0, tproj, tproj + 3*TE, tproj + 4*TE, tbsb, s1t,
      (const float*)d_in[11], zbb);
  // 5) out = zbb @ W_O + b_O  (output dtype follows the detected mode)
  gemm_tile<bf16, bf16, bf16, true, false><<<dim3(8,4,1), 256, 0, stream>>>(
      flag, 1, zbb, (const bf16*)d_in[13], (bf16*)d_out, (const bf16*)d_in[14],
      512, 512, 512, 512, 0, 0, 0, 0);
  gemm_tile<bf16, float, float, true, false><<<dim3(8,4,1), 256, 0, stream>>>(
      flag, 0, zbb, (const float*)d_in[13], (float*)d_out, (const float*)d_in[14],
      512, 512, 512, 512, 0, 0, 0, 0);
}

// Round 5
// 359.649 us; speedup vs baseline: 2.6750x; 2.6750x over previous
//
#include <hip/hip_runtime.h>
#include <hip/hip_bf16.h>

// TrittentionCube on MI355X. B=1, P=256, D=512, N=8, H=64. Round 5: MFMA tri_attn.
// Input dtype (bf16 vs fp32) resolved at runtime via probe; both variants launched,
// gated on the flag (graph-safe). Workspace: 3.53 MB (<= round-4 known-good 3.57).
//
//   ta..te[p,n,h] = x @ W_* + b_*        (fused proj kernel; td/te written TRANSPOSED:
//                                         tdT[n][h][p], teT[n][g][q] — for MFMA B-frags)
//   tbs[q,j]  = (1/64) sum_n tb[q,n,j]   (bf16)
//   s1t[r][(i,j)] = sum_{n,k} tc[r,(n,k)] W_K[n,i,j,k]   (strided-B GEMM, bf16)
//   per (n,r) block, all MFMA 16x16x32_bf16:
//     c[q,i]  = tbs(q,:)·s1t[r](i,:)           -> LDS [256][72] bf16 (padded)
//     E[p,q]  = exp(ta[p,:]·c[q,:]) for p<q<r  -> per-wave LDS [64][40] bf16, chunked q:32
//     T[p,g] += E·teT[n]                        (accumulators), Z = sum E
//     S[g,h]  = T^T·tdT[n]  (K=256)            -> LDS fp32 [64][68]
//     z[r,n,f] = (1/Z) sum_{g,h} S[g,h]*W_V[n,h,g,f]   (VALU, L2-resident W_V)
//   out[r,d] = zb @ W_O + b_O

typedef __hip_bfloat16 bf16;
typedef __attribute__((ext_vector_type(8))) short short8;
typedef __attribute__((ext_vector_type(4))) float floatx4;

__device__ __forceinline__ float ldf(const float* p){ return *p; }
__device__ __forceinline__ float ldf(const bf16* p){ return __bfloat162float(*p); }
__device__ __forceinline__ void  stf(float* p, float v){ *p = v; }
__device__ __forceinline__ void  stf(bf16*  p, float v){ *p = __float2bfloat16(v); }

__device__ __forceinline__ floatx4 mfma16(short8 a, short8 b, floatx4 c){
  return __builtin_amdgcn_mfma_f32_16x16x32_bf16(a, b, c, 0, 0, 0);
}
__device__ __forceinline__ short8 ld_g8(const bf16* p){
  return *reinterpret_cast<const short8*>(p);
}

// Input-dtype probe: flag=1 if bf16, 0 if fp32 (low 16 bits of fp32 words are
// uniform mantissa bits; of packed bf16 pairs they are sane bf16 values).
__global__ void dtype_probe(const unsigned* __restrict__ x, int* __restrict__ flag)
{
  int t = threadIdx.x;              // 64 threads
  int cnt = 0;
  #pragma unroll
  for (int k = 0; k < 4; k++) {
    unsigned w = x[t*4 + k];
    unsigned lo = w & 0xFFFFu;
    unsigned e  = (lo >> 7) & 0xFFu;
    if (lo == 0u || (e >= 90u && e <= 145u)) cnt++;
  }
  #pragma unroll
  for (int off = 32; off; off >>= 1) cnt += __shfl_down(cnt, off);
  if (t == 0) *flag = (cnt >= 160) ? 1 : 0;
}

// Fused 5-projection kernel: t_j[p,n,h] = x @ W_j[n] + b_j[n].
// j<3 ("ta","tb","tc"): normal layout [p][n*64+h].
// j>=3 ("td","te"): TRANSPOSED layout [n][h][p] (tdT/teT for MFMA B-operands).
template<typename TI>
__global__ __launch_bounds__(256) void proj_kern(
    const int* __restrict__ gate, int want, const TI* __restrict__ x,
    const TI* __restrict__ W0, const TI* __restrict__ b0,
    const TI* __restrict__ W1, const TI* __restrict__ b1,
    const TI* __restrict__ W2, const TI* __restrict__ b2,
    const TI* __restrict__ W3, const TI* __restrict__ b3,
    const TI* __restrict__ W4, const TI* __restrict__ b4,
    bf16* __restrict__ tproj)
{
  if (*gate != want) return;
  const TI* Ws[5] = {W0, W1, W2, W3, W4};
  const TI* bs[5] = {b0, b1, b2, b3, b4};
  const int bz = blockIdx.z, j = bz >> 3, n = bz & 7;
  const TI* B    = Ws[j] + (size_t)n * 32768;   // [d][h] row-major, ldb=64
  const TI* bias = bs[j] + n * 64;
  bf16* out = tproj + (size_t)j * 131072;
  const int m0 = blockIdx.y * 64;
  __shared__ float As[16][64];
  __shared__ float Bs[16][64];
  const int t = threadIdx.x, tx = t & 15, ty = t >> 4;
  float acc[4][4] = {};
  for (int k0 = 0; k0 < 512; k0 += 16) {
    { int m = t >> 2, kk = (t & 3) * 4;
      const TI* ap = x + (size_t)(m0 + m) * 512 + (k0 + kk);
      float a0 = ldf(ap+0), a1 = ldf(ap+1), a2 = ldf(ap+2), a3 = ldf(ap+3);
      As[kk+0][m] = a0; As[kk+1][m] = a1; As[kk+2][m] = a2; As[kk+3][m] = a3; }
    { int kk = t >> 4, nn = (t & 15) * 4;
      const TI* bp = B + (size_t)(k0 + kk) * 64 + nn;
      Bs[kk][nn+0] = ldf(bp+0); Bs[kk][nn+1] = ldf(bp+1);
      Bs[kk][nn+2] = ldf(bp+2); Bs[kk][nn+3] = ldf(bp+3); }
    __syncthreads();
    #pragma unroll
    for (int kk = 0; kk < 16; kk++) {
      float4 a4 = *reinterpret_cast<const float4*>(&As[kk][ty*4]);
      float4 b4 = *reinterpret_cast<const float4*>(&Bs[kk][tx*4]);
      float av[4] = {a4.x,a4.y,a4.z,a4.w}, bv[4] = {b4.x,b4.y,b4.z,b4.w};
      #pragma unroll
      for (int im = 0; im < 4; im++)
        #pragma unroll
        for (int in = 0; in < 4; in++) acc[im][in] += av[im] * bv[in];
    }
    __syncthreads();
  }
  #pragma unroll
  for (int im = 0; im < 4; im++)
    #pragma unroll
    for (int in = 0; in < 4; in++) {
      float v = acc[im][in] + ldf(bias + tx*4 + in);
      int p = m0 + ty*4 + im, h = tx*4 + in;
      if (j < 3) out[(size_t)p * 512 + n*64 + h] = __float2bfloat16(v);
      else       out[(size_t)n * 16384 + (size_t)h * 256 + p] = __float2bfloat16(v);
    }
}

// Generic 64x64-tile GEMM (used for s1t and final out); BTRANS = W_K strided read.
template<typename TA, typename TB, typename TC, bool BIAS, bool BTRANS>
__global__ __launch_bounds__(256) void gemm_tile(
    const int* __restrict__ gate, int want,
    const TA* __restrict__ A, const TB* __restrict__ B, TC* __restrict__ C,
    const TB* __restrict__ bias,
    int Ncols, int K, int lda, int ldc,
    long sA, long sB, long sC, long sBias)
{
  if (*gate != want) return;
  const int bz = blockIdx.z;
  A += bz * sA; B += bz * sB; C += bz * sC;
  const int m0 = blockIdx.y * 64, n0 = blockIdx.x * 64;
  __shared__ float As[16][64];
  __shared__ float Bs[16][64];
  const int t = threadIdx.x, tx = t & 15, ty = t >> 4;
  float acc[4][4] = {};
  for (int k0 = 0; k0 < K; k0 += 16) {
    { int m = t >> 2, kk = (t & 3) * 4;
      const TA* ap = A + (size_t)(m0 + m) * lda + (k0 + kk);
      float a0 = ldf(ap+0), a1 = ldf(ap+1), a2 = ldf(ap+2), a3 = ldf(ap+3);
      As[kk+0][m] = a0; As[kk+1][m] = a1; As[kk+2][m] = a2; As[kk+3][m] = a3; }
    { int kk = t >> 4, nn = (t & 15) * 4;
      if constexpr (BTRANS) {
        int kr = k0 + kk;
        const TB* bp = B + (size_t)(kr >> 6) * 262144 + (size_t)(kr & 63);
        Bs[kk][nn+0] = ldf(bp + (size_t)(n0+nn+0) * 64);
        Bs[kk][nn+1] = ldf(bp + (size_t)(n0+nn+1) * 64);
        Bs[kk][nn+2] = ldf(bp + (size_t)(n0+nn+2) * 64);
        Bs[kk][nn+3] = ldf(bp + (size_t)(n0+nn+3) * 64);
      } else {
        const TB* bp = B + (size_t)(k0 + kk) * Ncols + (n0 + nn);
        Bs[kk][nn+0] = ldf(bp+0); Bs[kk][nn+1] = ldf(bp+1);
        Bs[kk][nn+2] = ldf(bp+2); Bs[kk][nn+3] = ldf(bp+3);
      } }
    __syncthreads();
    #pragma unroll
    for (int kk = 0; kk < 16; kk++) {
      float4 a4 = *reinterpret_cast<const float4*>(&As[kk][ty*4]);
      float4 b4 = *reinterpret_cast<const float4*>(&Bs[kk][tx*4]);
      float av[4] = {a4.x,a4.y,a4.z,a4.w}, bv[4] = {b4.x,b4.y,b4.z,b4.w};
      #pragma unroll
      for (int im = 0; im < 4; im++)
        #pragma unroll
        for (int in = 0; in < 4; in++) acc[im][in] += av[im] * bv[in];
    }
    __syncthreads();
  }
  #pragma unroll
  for (int im = 0; im < 4; im++) {
    TC* cp = C + (size_t)(m0 + ty*4 + im) * ldc + n0 + tx*4;
    #pragma unroll
    for (int in = 0; in < 4; in++) {
      float v = acc[im][in];
      if constexpr (BIAS) v += ldf(bias + bz * sBias + n0 + tx*4 + in);
      stf(cp + in, v);
    }
  }
}

// tbs[q][j] = (1/64) * sum_n tb[q][n][j]  -> bf16 [q][64]
__global__ __launch_bounds__(256) void tbs_kern(const bf16* __restrict__ tb,
                                                bf16* __restrict__ tbsbf)
{
  int t = blockIdx.x * 256 + threadIdx.x;   // 0..16383
  int q = t >> 6, j = t & 63;
  float s = 0.f;
  #pragma unroll
  for (int n = 0; n < 8; n++) s += ldf(tb + q*512 + n*64 + j);
  tbsbf[t] = __float2bfloat16(s * 0.015625f);
}

// Per-(n,r) MFMA attention. LDS (57856 B):
//   [0,36864)      phase1: c [256][72] bf16 (pad->2-way max); phase2: Tt [64][264] bf16
//   [36864,57344)  per-wave Ew [64][40] bf16 (x4); phase2: S [64][68] fp32
//   [57344,57856)  scr (Z partials, z cross-wave reduce)
template<typename TW>
__global__ __launch_bounds__(256) void tri_attn(
    const int* __restrict__ gate, int want,
    const bf16* __restrict__ ta,     // [p][n*64+h]
    const bf16* __restrict__ tbsbf,  // [q][64]
    const bf16* __restrict__ s1t,    // [r][i*64+j]
    const bf16* __restrict__ tdT,    // [n][h][p]
    const bf16* __restrict__ teT,    // [n][g][q]
    const TW*   __restrict__ WV,     // [n][h][g][f]
    bf16* __restrict__ zb)           // [r][n*64+f]
{
  if (*gate != want) return;
  __shared__ __align__(16) char smb[57856];
  const int bx = blockIdx.x;
  const int n = bx & 7;               // n -> XCD affinity (W_V[n], teT/tdT L2 residency)
  const int r = 255 - (bx >> 3);      // big-r first
  const int t = threadIdx.x;
  const int wid = t >> 6, lane = t & 63, quad = lane >> 4, l16 = lane & 15;
  bf16* zrow = zb + r * 512 + n * 64;
  if (r < 2) { if (t < 64) stf(zrow + t, 0.f); return; }
  const int pw = wid * 64;            // wave's p-stripe (and q-stripe in phase 1)

  // ---- Phase 1: c[q][i] = tbs[q,:]·s1t[r][i,:]  (MFMA; rows q<1 or q>=r zeroed)
  {
    const bf16* s1r = s1t + (size_t)r * 4096;
    short8 bfr[4][2];
    #pragma unroll
    for (int it = 0; it < 4; it++)
      #pragma unroll
      for (int kc = 0; kc < 2; kc++)
        bfr[it][kc] = ld_g8(s1r + (it*16 + l16)*64 + kc*32 + quad*8);
    #pragma unroll
    for (int qt = 0; qt < 4; qt++) {
      const int q0 = pw + qt*16;
      short8 af0 = ld_g8(tbsbf + (q0 + l16)*64 + quad*8);
      short8 af1 = ld_g8(tbsbf + (q0 + l16)*64 + 32 + quad*8);
      #pragma unroll
      for (int it = 0; it < 4; it++) {
        floatx4 acc = {0.f, 0.f, 0.f, 0.f};
        acc = mfma16(af0, bfr[it][0], acc);
        acc = mfma16(af1, bfr[it][1], acc);
        #pragma unroll
        for (int reg = 0; reg < 4; reg++) {
          int q = q0 + quad*4 + reg;
          float v = (q >= 1 && q < r) ? acc[reg] : 0.f;
          *reinterpret_cast<bf16*>(smb + q*144 + (it*16 + l16)*2) = __float2bfloat16(v);
        }
      }
    }
  }
  // ta A-fragments (persistent across the whole q-loop)
  short8 taf[4][2];
  #pragma unroll
  for (int pt = 0; pt < 4; pt++)
    #pragma unroll
    for (int kc = 0; kc < 2; kc++)
      taf[pt][kc] = ld_g8(ta + (size_t)(pw + pt*16 + l16)*512 + n*64 + kc*32 + quad*8);
  __syncthreads();                    // c visible to all waves

  // ---- Main loop: E chunk (all p x 32 q), per-wave private; T += E·teT
  floatx4 Tacc[4][4];
  #pragma unroll
  for (int pt = 0; pt < 4; pt++)
    #pragma unroll
    for (int gt = 0; gt < 4; gt++) Tacc[pt][gt] = (floatx4){0.f, 0.f, 0.f, 0.f};
  float Zp = 0.f;
  char* EwB = smb + 36864 + wid * 5120;          // [64][40] bf16, per wave
  const int nch = ((r - 1) >> 5) + 1;
  for (int ch = 0; ch < nch; ch++) {
    const int qc = ch * 32;
    if (qc + 31 <= pw) continue;      // whole chunk masked for this wave (q <= p)
    short8 cfr[2][2];
    #pragma unroll
    for (int qt2 = 0; qt2 < 2; qt2++)
      #pragma unroll
      for (int kc = 0; kc < 2; kc++)
        cfr[qt2][kc] = *reinterpret_cast<const short8*>(
            smb + (qc + qt2*16 + l16)*144 + (kc*32 + quad*8)*2);
    #pragma unroll
    for (int qt2 = 0; qt2 < 2; qt2++)
      #pragma unroll
      for (int pt = 0; pt < 4; pt++) {
        floatx4 acc = {0.f, 0.f, 0.f, 0.f};
        acc = mfma16(taf[pt][0], cfr[qt2][0], acc);
        acc = mfma16(taf[pt][1], cfr[qt2][1], acc);
        #pragma unroll
        for (int reg = 0; reg < 4; reg++) {
          int p = pw + pt*16 + quad*4 + reg;
          int q = qc + qt2*16 + l16;
          float sv = fminf(fmaxf(acc[reg], -60.f), 60.f);  // fmaxf eats NaN
          float e = (p < q && q < r) ? __expf(sv) : 0.f;
          Zp += e;
          *reinterpret_cast<bf16*>(EwB + (pt*16 + quad*4 + reg)*80
                                       + (qt2*16 + l16)*2) = __float2bfloat16(e);
        }
      }
    short8 tef[4];
    #pragma unroll
    for (int gt = 0; gt < 4; gt++)
      tef[gt] = ld_g8(teT + (size_t)n*16384 + (gt*16 + l16)*256 + qc + quad*8);
    #pragma unroll
    for (int pt = 0; pt < 4; pt++) {
      short8 ef = *reinterpret_cast<const short8*>(EwB + (pt*16 + l16)*80 + quad*16);
      #pragma unroll
      for (int gt = 0; gt < 4; gt++)
        Tacc[pt][gt] = mfma16(ef, tef[gt], Tacc[pt][gt]);
    }
  }
  // Z: wave reduce -> scr; barrier also closes all c reads
  #pragma unroll
  for (int off = 32; off; off >>= 1) Zp += __shfl_down(Zp, off);
  float* scr = reinterpret_cast<float*>(smb + 57344);
  if (lane == 0) scr[wid] = Zp;
  __syncthreads();
  const float rinv = 1.f / (scr[0] + scr[1] + scr[2] + scr[3]);

  // ---- Tt[g][p] (bf16, pad 264) over dead c region
  #pragma unroll
  for (int pt = 0; pt < 4; pt++)
    #pragma unroll
    for (int gt = 0; gt < 4; gt++)
      #pragma unroll
      for (int reg = 0; reg < 4; reg++) {
        int g = gt*16 + l16;
        int p = pw + pt*16 + quad*4 + reg;
        *reinterpret_cast<bf16*>(smb + g*528 + p*2) = __float2bfloat16(Tacc[pt][gt][reg]);
      }
  __syncthreads();                    // Tt visible cross-wave (rinv read before this)

  // ---- S[g][h] = T^T·tdT (K=256); wave w computes rows g in [16w,16w+16)
  float* Sf = reinterpret_cast<float*>(smb + 36864);   // [64][68] fp32
  {
    short8 Taf[8];
    #pragma unroll
    for (int kc = 0; kc < 8; kc++)
      Taf[kc] = *reinterpret_cast<const short8*>(
          smb + (wid*16 + l16)*528 + (kc*32 + quad*8)*2);
    #pragma unroll
    for (int ht = 0; ht < 4; ht++) {
      floatx4 acc = {0.f, 0.f, 0.f, 0.f};
      #pragma unroll
      for (int kc = 0; kc < 8; kc++) {
        short8 bfragd = ld_g8(tdT + (size_t)n*16384 + (ht*16 + l16)*256 + kc*32 + quad*8);
        acc = mfma16(Taf[kc], bfragd, acc);
      }
      #pragma unroll
      for (int reg = 0; reg < 4; reg++)
        Sf[(wid*16 + quad*4 + reg) * 68 + ht*16 + l16] = acc[reg];
    }
  }
  // ---- z[f] partial over g in [16*wid, +16): sum_{g,h} S[g,h]*WV[n,h,g,f]
  // (wave reads only its own S rows -> no barrier needed before this)
  const int f = lane, g0 = wid * 16;
  const TW* wvn = WV + (size_t)n * 262144 + f;
  float zacc = 0.f;
  for (int k = 0; k < 16; k++) {
    const float* Srow = Sf + (size_t)(g0 + k) * 68;
    const TW* wvg = wvn + (size_t)(g0 + k) * 64;
    #pragma unroll
    for (int h4 = 0; h4 < 16; h4++) {
      float4 s4 = *reinterpret_cast<const float4*>(Srow + h4 * 4);
      zacc += s4.x * ldf(wvg + (size_t)(4*h4+0) * 4096);
      zacc += s4.y * ldf(wvg + (size_t)(4*h4+1) * 4096);
      zacc += s4.z * ldf(wvg + (size_t)(4*h4+2) * 4096);
      zacc += s4.w * ldf(wvg + (size_t)(4*h4+3) * 4096);
    }
  }
  if (wid >= 2) scr[(wid - 2) * 64 + f] = zacc;
  __syncthreads();
  if (wid < 2) zacc += scr[wid * 64 + f];
  __syncthreads();
  if (wid == 1) scr[f] = zacc;
  __syncthreads();
  if (wid == 0) stf(zrow + f, (zacc + scr[f]) * rinv);
}

extern "C" void kernel_launch(void* const* d_in, const int* in_sizes, int n_in,
                              void* d_out, int out_size, void* d_ws, size_t ws_size,
                              hipStream_t stream)
{
  (void)in_sizes; (void)n_in; (void)out_size; (void)ws_size;
  // Workspace (bytes), total 3,703,040 (~3.53 MB, <= round-4 known-good):
  //   flag  [0,4) ; tproj bf16 [256, 1310976)  (j=0 ta, j=1 tb, j=2 tc normal
  //                 [p][n*64+h]; j=3 tdT [n][h][p]; j=4 teT [n][g][q])
  //   tbsbf bf16 [1310976, 1343744) ; s1t bf16 [1343744, 3440896)
  //   zbb   bf16 [3440896, 3703040)
  char* wsb = (char*)d_ws;
  int*  flag  = (int*)wsb;
  bf16* tproj = (bf16*)(wsb + 256);
  bf16* tbsbf = (bf16*)(wsb + 1310976);
  bf16* s1t   = (bf16*)(wsb + 1343744);
  bf16* zbb   = (bf16*)(wsb + 3440896);
  const long TE = 131072;

  dtype_probe<<<1, 64, 0, stream>>>((const unsigned*)d_in[0], flag);

  // 1) fused projections (both dtype variants, gated)
  proj_kern<bf16><<<dim3(1,4,40), 256, 0, stream>>>(
      flag, 1, (const bf16*)d_in[0],
      (const bf16*)d_in[1], (const bf16*)d_in[2], (const bf16*)d_in[3], (const bf16*)d_in[4],
      (const bf16*)d_in[5], (const bf16*)d_in[6], (const bf16*)d_in[7], (const bf16*)d_in[8],
      (const bf16*)d_in[9], (const bf16*)d_in[10], tproj);
  proj_kern<float><<<dim3(1,4,40), 256, 0, stream>>>(
      flag, 0, (const float*)d_in[0],
      (const float*)d_in[1], (const float*)d_in[2], (const float*)d_in[3], (const float*)d_in[4],
      (const float*)d_in[5], (const float*)d_in[6], (const float*)d_in[7], (const float*)d_in[8],
      (const float*)d_in[9], (const float*)d_in[10], tproj);
  // 2) tbs (bf16, 1/64 folded)
  tbs_kern<<<64, 256, 0, stream>>>(tproj + 1*TE, tbsbf);
  // 3) s1t[r][(i,j)] = tc @ W_K (strided-B)
  gemm_tile<bf16, bf16, bf16, false, true><<<dim3(64,4,1), 256, 0, stream>>>(
      flag, 1, tproj + 2*TE, (const bf16*)d_in[12], s1t, (const bf16*)nullptr,
      4096, 512, 512, 4096, 0, 0, 0, 0);
  gemm_tile<bf16, float, bf16, false, true><<<dim3(64,4,1), 256, 0, stream>>>(
      flag, 0, tproj + 2*TE, (const float*)d_in[12], s1t, (const float*)nullptr,
      4096, 512, 512, 4096, 0, 0, 0, 0);
  // 4) MFMA attention
  tri_attn<bf16><<<2048, 256, 0, stream>>>(
      flag, 1, tproj, tbsbf, s1t, tproj + 3*TE, tproj + 4*TE,
      (const bf16*)d_in[11], zbb);
  tri_attn<float><<<2048, 256, 0, stream>>>(
      flag, 0, tproj, tbsbf, s1t, tproj + 3*TE, tproj + 4*TE,
      (const float*)d_in[11], zbb);
  // 5) out = zbb @ W_O + b_O
  gemm_tile<bf16, bf16, bf16, true, false><<<dim3(8,4,1), 256, 0, stream>>>(
      flag, 1, zbb, (const bf16*)d_in[13], (bf16*)d_out, (const bf16*)d_in[14],
      512, 512, 512, 512, 0, 0, 0, 0);
  gemm_tile<bf16, float, float, true, false><<<dim3(8,4,1), 256, 0, stream>>>(
      flag, 0, zbb, (const float*)d_in[13], (float*)d_out, (const float*)d_in[14],
      512, 512, 512, 512, 0, 0, 0, 0);
}